// Round 13
// baseline (856.376 us; speedup 1.0000x reference)
//
#include <hip/hip_runtime.h>
#include <hip/hip_bf16.h>
#include <hip/hip_cooperative_groups.h>

namespace cg = cooperative_groups;

// Problem constants
#define NN 50000
#define EE 800000
#define NFR 513
#define NMEL 128
#define HC 128      // H*C = 4*32

typedef __bf16 bf16x8 __attribute__((ext_vector_type(8)));
typedef float floatx4 __attribute__((ext_vector_type(4)));

// 16-byte load at 4-byte alignment (x rows are 2052 B = 4B-aligned)
struct __attribute__((packed, aligned(4))) u4a { unsigned x, y, z, w; };

__device__ __forceinline__ unsigned short f2b(float f) {   // RNE fp32->bf16 bits
    unsigned u = __float_as_uint(f);
    u = (u + 0x7FFFu + ((u >> 16) & 1u)) >> 16;
    return (unsigned short)u;
}
__device__ __forceinline__ unsigned short f2bu(unsigned u) {  // RNE on raw fp32 bits
    u = (u + 0x7FFFu + ((u >> 16) & 1u)) >> 16;
    return (unsigned short)u;
}
__device__ __forceinline__ float b2f(unsigned short s) {
    return __uint_as_float(((unsigned)s) << 16);
}
__device__ __forceinline__ float lexp(float a) {           // exp(leaky_relu(a, 0.2))
    a = a > 0.f ? a : 0.2f * a;
    return __expf(a);
}
__device__ __forceinline__ void stf(__hip_bfloat16* p, long i, float v) {
    ((unsigned short*)p)[i] = f2b(v);
}

// ---------------- k_prep: fused {fbWgT = (fb@Wg)^T bf16 pad-544} + {W1T} + {W2T} ----------------
// blockIdx ranges: [0,18) gemm tiles (9x2); [18,146) W1 transpose; [146,274) W2 transpose.
// All three are mutually independent — one launch instead of three (launch-overhead cut).
__global__ __launch_bounds__(256) void k_prep(const float* __restrict__ fb, const float* __restrict__ Wg,
                                              __hip_bfloat16* __restrict__ fbWgT,
                                              const float* __restrict__ W1, __hip_bfloat16* __restrict__ W1T,
                                              const float* __restrict__ W2, __hip_bfloat16* __restrict__ W2T)
{
    const int b = blockIdx.x, t = threadIdx.x;
    if (b >= 18) {
        if (b < 146) {      // W1T[n*128+k] = bf16(W1[k*256+n]), K=KP=128, N=256
            int id = (b - 18) * 256 + t;
            int n = id >> 7, k = id & 127;
            ((unsigned short*)W1T)[id] = f2b(W1[(long)k * 256 + n]);
        } else {            // W2T[n*256+k] = bf16(W2[k*128+n]), K=KP=256, N=128
            int id = (b - 146) * 256 + t;
            int n = id >> 8, k = id & 255;
            ((unsigned short*)W2T)[id] = f2b(W2[(long)k * 128 + n]);
        }
        return;             // before any barrier — block-uniform
    }
    // small fp32 GEMM tile: M=NFR(513), K=NMEL(128), Nn=HC(128); EPI2 store transposed bf16 stride 544
    __shared__ float As[16][68];
    __shared__ float Bs[16][68];
    const int row0 = (b % 9) * 64;
    const int col0 = (b / 9) * 64;
    const int tc = t & 15, tr = t >> 4;
    float acc[4][4] = {};

    for (int kb = 0; kb < NMEL; kb += 16) {
        #pragma unroll
        for (int i = 0; i < 4; ++i) {
            int idx = i * 256 + t;
            int r = idx >> 4, k = idx & 15;
            int gr = row0 + r, gk = kb + k;
            float v = 0.f;
            if (gr < NFR) v = fb[(long)gr * NMEL + gk];
            As[k][r] = v;
        }
        #pragma unroll
        for (int i = 0; i < 4; ++i) {
            int idx = i * 256 + t;
            int c = idx & 63, k = idx >> 6;
            int gk = kb + k, gc = col0 + c;
            Bs[k][c] = Wg[(long)gk * HC + gc];
        }
        __syncthreads();
        #pragma unroll
        for (int kk = 0; kk < 16; ++kk) {
            float4 av = *reinterpret_cast<const float4*>(&As[kk][tr << 2]);
            float4 bv = *reinterpret_cast<const float4*>(&Bs[kk][tc << 2]);
            float a[4] = {av.x, av.y, av.z, av.w};
            float bb[4] = {bv.x, bv.y, bv.z, bv.w};
            #pragma unroll
            for (int i = 0; i < 4; ++i)
                #pragma unroll
                for (int j = 0; j < 4; ++j)
                    acc[i][j] += a[i] * bb[j];
        }
        __syncthreads();
    }
    #pragma unroll
    for (int i = 0; i < 4; ++i) {
        int gr = row0 + (tr << 2) + i;
        if (gr >= NFR) continue;
        #pragma unroll
        for (int j = 0; j < 4; ++j) {
            int gc = col0 + (tc << 2) + j;
            ((unsigned short*)fbWgT)[(long)gc * 544 + gr] = f2b(acc[i][j]);
        }
    }
}

// ---------------- MFMA bf16 GEMM: C[M,Nn] = A[M,K] @ Bt[Nn,KB]^T ----------------
// R3/R9 structure (mgemm#1 at its ~62-66us structural floor; R1-R9 ablations flat).
// EPI=4 adds fused attention coeffs (R11-verified) AND absorbs k_hist: blocks >= 782
// do the edge histogram and exit before any barrier (hist is GEMM-independent, its
// ~10us hides under the 66us GEMM).
#define PS 40   // LDS row stride in bf16 units (80 B) -> 2-way bank conflicts only (free)

template<typename T> struct ARegs;
template<> struct ARegs<float> { unsigned v[8]; };        // raw fp32 bits
template<> struct ARegs<__hip_bfloat16> { uint4 v; };

__device__ __forceinline__ void loadA_r(const float* __restrict__ A, ARegs<float>& r, int t,
                                        int row0, int M, int K, int kb)
{
    #pragma unroll
    for (int g = 0; g < 2; ++g) {
        int q = g * 256 + t;            // 0..511 quads (64 rows x 8 quads of 16B)
        int row = q >> 3, k4 = (q & 7) * 4;
        int gr = row0 + row, gk = kb + k4;
        unsigned f0 = 0, f1 = 0, f2 = 0, f3 = 0;
        if (gr < M) {
            const float* ap = A + (long)gr * K + gk;
            if (gk + 3 < K) {           // vector path: single dwordx4 at 4B alignment
                u4a u = *reinterpret_cast<const u4a*>(ap);
                f0 = u.x; f1 = u.y; f2 = u.z; f3 = u.w;
            } else {                    // K-boundary chunk (last kb iter only)
                if (gk + 0 < K) f0 = __float_as_uint(ap[0]);
                if (gk + 1 < K) f1 = __float_as_uint(ap[1]);
                if (gk + 2 < K) f2 = __float_as_uint(ap[2]);
            }
        }
        r.v[g * 4 + 0] = f0; r.v[g * 4 + 1] = f1;
        r.v[g * 4 + 2] = f2; r.v[g * 4 + 3] = f3;
    }
}

__device__ __forceinline__ void writeA_r(unsigned short* As, const ARegs<float>& r, int t)
{
    #pragma unroll
    for (int g = 0; g < 2; ++g) {
        int q = g * 256 + t;
        int row = q >> 3, k4 = (q & 7) * 4;
        ushort4 pk;
        pk.x = f2bu(r.v[g * 4 + 0]); pk.y = f2bu(r.v[g * 4 + 1]);
        pk.z = f2bu(r.v[g * 4 + 2]); pk.w = f2bu(r.v[g * 4 + 3]);
        *reinterpret_cast<ushort4*>(&As[row * PS + k4]) = pk;
    }
}

__device__ __forceinline__ void loadA_r(const __hip_bfloat16* __restrict__ A, ARegs<__hip_bfloat16>& r,
                                        int t, int row0, int M, int K, int kb)
{
    int row = t >> 2, k8 = (t & 3) * 8;  // 256 16B-chunks (64 rows x 4)
    int gr = row0 + row;
    uint4 val = make_uint4(0, 0, 0, 0);
    if (gr < M) val = *reinterpret_cast<const uint4*>(A + (long)gr * K + kb + k8);
    r.v = val;
}

__device__ __forceinline__ void writeA_r(unsigned short* As, const ARegs<__hip_bfloat16>& r, int t)
{
    int row = t >> 2, k8 = (t & 3) * 8;
    *reinterpret_cast<uint4*>(&As[row * PS + k8]) = r.v;
}

__device__ __forceinline__ void loadB_r(const __hip_bfloat16* __restrict__ Bt, uint4* bR, int t,
                                        int col0, int Nn, int KB, int kb)
{
    #pragma unroll
    for (int g = 0; g < 2; ++g) {
        int c = g * 256 + t;            // 0..511 16B-chunks (128 rows x 4)
        int row = c >> 2, k8 = (c & 3) * 8;
        int gn = col0 + row;
        uint4 val = make_uint4(0, 0, 0, 0);
        if (gn < Nn) val = *reinterpret_cast<const uint4*>(Bt + (long)gn * KB + kb + k8);
        bR[g] = val;
    }
}

__device__ __forceinline__ void writeB_r(unsigned short* Bs, const uint4* bR, int t)
{
    #pragma unroll
    for (int g = 0; g < 2; ++g) {
        int c = g * 256 + t;
        int row = c >> 2, k8 = (c & 3) * 8;
        *reinterpret_cast<uint4*>(&Bs[row * PS + k8]) = bR[g];
    }
}

// EPI: 4 = plain C + fused attention coeffs + absorbed k_hist (blocks >= 782)
template<int EPI, typename TA, typename TC>
__global__ __launch_bounds__(256) void mgemm(const TA* __restrict__ A,
                                             const __hip_bfloat16* __restrict__ Bt,
                                             TC* __restrict__ C,
                                             int M, int Nn, int K, int KB,
                                             const float* __restrict__ bias,
                                             const float* __restrict__ pf1,
                                             const float* __restrict__ pf2,
                                             float* __restrict__ po1,
                                             float* __restrict__ po2,
                                             const int* __restrict__ ei,
                                             int* __restrict__ hist)
{
    if (EPI == 4 && blockIdx.x >= 782) {
        int e = (blockIdx.x - 782) * 256 + (int)threadIdx.x;
        if (e < EE) atomicAdd(&hist[ei[EE + e]], 1);
        return;                          // before any barrier — block-uniform
    }

    __shared__ unsigned short As[2][64 * PS];
    __shared__ unsigned short Bs[2][128 * PS];

    const int t = threadIdx.x;
    const int row0 = blockIdx.x * 64;
    const int col0 = blockIdx.y * 128;
    const int wave = t >> 6, lane = t & 63;
    const int wm = (wave >> 1) * 32, wn = (wave & 1) * 64;
    const int lm = lane & 15, kq = lane >> 4;

    floatx4 acc[2][4];
    #pragma unroll
    for (int i = 0; i < 2; ++i)
        #pragma unroll
        for (int j = 0; j < 4; ++j)
            acc[i][j] = 0.f;

    ARegs<TA> aR;
    uint4 bR[2];
    loadA_r(A, aR, t, row0, M, K, 0);
    loadB_r(Bt, bR, t, col0, Nn, KB, 0);

    const int nIter = KB >> 5;
    int b = 0;
    for (int it = 0; it < nIter; ++it) {
        writeA_r(As[b], aR, t);
        writeB_r(Bs[b], bR, t);
        if (it + 1 < nIter) {
            loadA_r(A, aR, t, row0, M, K, (it + 1) * 32);
            loadB_r(Bt, bR, t, col0, Nn, KB, (it + 1) * 32);
        }
        asm volatile("s_waitcnt lgkmcnt(0)" ::: "memory");
        __builtin_amdgcn_s_barrier();
        __builtin_amdgcn_sched_barrier(0);

        bf16x8 af[2], bf[4];
        #pragma unroll
        for (int i = 0; i < 2; ++i)
            af[i] = *reinterpret_cast<const bf16x8*>(&As[b][(wm + i * 16 + lm) * PS + kq * 8]);
        #pragma unroll
        for (int j = 0; j < 4; ++j)
            bf[j] = *reinterpret_cast<const bf16x8*>(&Bs[b][(wn + j * 16 + lm) * PS + kq * 8]);
        #pragma unroll
        for (int i = 0; i < 2; ++i)
            #pragma unroll
            for (int j = 0; j < 4; ++j)
                acc[i][j] = __builtin_amdgcn_mfma_f32_16x16x32_bf16(af[i], bf[j], acc[i][j], 0, 0, 0);
        b ^= 1;
    }

    // ---- epilogue: C write (verified mapping row=wm+i*16+kq*4+r, col=wn+j*16+lm) ----
    #pragma unroll
    for (int i = 0; i < 2; ++i) {
        #pragma unroll
        for (int r = 0; r < 4; ++r) {
            int gr = row0 + wm + i * 16 + kq * 4 + r;
            if (gr >= M) continue;
            #pragma unroll
            for (int j = 0; j < 4; ++j) {
                int gc = col0 + wn + j * 16 + lm;
                float v = acc[i][j][r];
                if (EPI == 1) { v += bias[gc]; v = v > 0.f ? v : 0.01f * v; }
                stf(C, (long)gr * Nn + gc, v);
            }
        }
    }

    // ---- EPI=4: fused attention coefficients from acc (R11-verified) ----
    if (EPI == 4) {
        float wsv[4], wdv[4];
        #pragma unroll
        for (int j = 0; j < 4; ++j) {
            int gc = wn + j * 16 + lm;      // col0 == 0 for mgemm#1
            wsv[j] = pf1[gc];
            wdv[j] = pf2[gc];
        }
        #pragma unroll
        for (int i = 0; i < 2; ++i) {
            #pragma unroll
            for (int r = 0; r < 4; ++r) {
                float s0 = acc[i][0][r] * wsv[0] + acc[i][1][r] * wsv[1];   // head wn>>5
                float s1 = acc[i][2][r] * wsv[2] + acc[i][3][r] * wsv[3];   // head (wn>>5)+1
                float d0 = acc[i][0][r] * wdv[0] + acc[i][1][r] * wdv[1];
                float d1 = acc[i][2][r] * wdv[2] + acc[i][3][r] * wdv[3];
                #pragma unroll
                for (int m = 1; m < 16; m <<= 1) {
                    s0 += __shfl_xor(s0, m); s1 += __shfl_xor(s1, m);
                    d0 += __shfl_xor(d0, m); d1 += __shfl_xor(d1, m);
                }
                if (lm == 0) {
                    int grow = row0 + wm + i * 16 + kq * 4 + r;
                    if (grow < M) {
                        int h0 = wn >> 5;                 // 0 or 2
                        po1[grow * 4 + h0]     = s0;
                        po1[grow * 4 + h0 + 1] = s1;
                        po2[grow * 4 + h0]     = d0;
                        po2[grow * 4 + h0 + 1] = d1;
                    }
                }
            }
        }
    }
}

// ---------------- k_graph (COOPERATIVE): scan1 -> scan2 -> scan3 -> fill -> agg ----------------
// Replaces 5 launches with 1; phases separated by grid.sync() (device-scope barrier+fence).
// Grid 1024 x 256 (4 blocks/CU — co-residency guaranteed by cooperative launch).
// All grid.sync() calls are unconditional (reached by every thread of every block);
// per-block __syncthreads are block-uniform. agg is grid-stride (wave per node).
__global__ __launch_bounds__(256) void k_graph(const int* __restrict__ hist,
                                               int* __restrict__ start,
                                               int* __restrict__ cursor,
                                               int* __restrict__ aux,
                                               const int* __restrict__ ei,
                                               int* __restrict__ sorted,
                                               const float* __restrict__ a_s,
                                               const float* __restrict__ a_d,
                                               const __hip_bfloat16* __restrict__ h,
                                               const float* __restrict__ bias_g,
                                               __hip_bfloat16* __restrict__ agg)
{
    cg::grid_group grid = cg::this_grid();
    const int t = threadIdx.x, bid = blockIdx.x;
    const int NCH = (NN + 255) / 256;        // 196 chunks
    __shared__ int sm[256];

    // Phase A: per-chunk exclusive scan of hist -> start; chunk totals -> aux
    if (bid < NCH) {
        int i = bid * 256 + t;
        int v = (i < NN) ? hist[i] : 0;
        sm[t] = v;
        __syncthreads();
        for (int off = 1; off < 256; off <<= 1) {
            int x = (t >= off) ? sm[t - off] : 0;
            __syncthreads();
            sm[t] += x;
            __syncthreads();
        }
        if (i < NN) start[i] = sm[t] - v;
        if (t == 255) aux[bid] = sm[255];
    }
    grid.sync();

    // Phase B: block 0 exclusive-scans aux[NCH]
    if (bid == 0) {
        int v = (t < NCH) ? aux[t] : 0;
        sm[t] = v;
        __syncthreads();
        for (int off = 1; off < 256; off <<= 1) {
            int x = (t >= off) ? sm[t - off] : 0;
            __syncthreads();
            sm[t] += x;
            __syncthreads();
        }
        if (t < NCH) aux[t] = sm[t] - v;
    }
    grid.sync();

    // Phase C: add chunk offsets; init cursor; start[NN]=EE
    if (bid < NCH) {
        int i = bid * 256 + t;
        if (i < NN) {
            int v = start[i] + aux[bid];
            start[i] = v;
            cursor[i] = v;
        }
    }
    if (bid == 0 && t == 0) start[NN] = EE;
    grid.sync();

    // Phase D: fill (grid-stride over edges)
    for (int e = bid * 256 + t; e < EE; e += (int)gridDim.x * 256) {
        int s = ei[e], d = ei[EE + e];
        int pos = atomicAdd(&cursor[d], 1);
        sorted[pos] = s;
    }
    grid.sync();

    // Phase E: gather-aggregate (wave per node, grid-stride, x4 unroll for MLP)
    {
        int wave = t >> 6, lane = t & 63;
        int hh = lane >> 4;
        for (int d = bid * 4 + wave; d < NN; d += (int)gridDim.x * 4) {
            float ad = a_d[d * 4 + hh];
            int e0 = start[d], e1 = start[d + 1];

            float ex = lexp(a_s[d * 4 + hh] + ad);
            unsigned hv = *reinterpret_cast<const unsigned*>(h + (long)d * HC + 2 * lane);
            float acc0 = ex * __uint_as_float(hv << 16);
            float acc1 = ex * __uint_as_float(hv & 0xffff0000u);
            float dsum = ex;

            int e = e0;
            for (; e + 4 <= e1; e += 4) {
                int s0 = sorted[e + 0], s1 = sorted[e + 1], s2 = sorted[e + 2], s3 = sorted[e + 3];
                float as0 = a_s[s0 * 4 + hh], as1 = a_s[s1 * 4 + hh];
                float as2 = a_s[s2 * 4 + hh], as3 = a_s[s3 * 4 + hh];
                unsigned h0 = *reinterpret_cast<const unsigned*>(h + (long)s0 * HC + 2 * lane);
                unsigned h1 = *reinterpret_cast<const unsigned*>(h + (long)s1 * HC + 2 * lane);
                unsigned h2 = *reinterpret_cast<const unsigned*>(h + (long)s2 * HC + 2 * lane);
                unsigned h3 = *reinterpret_cast<const unsigned*>(h + (long)s3 * HC + 2 * lane);
                float x0 = lexp(as0 + ad), x1 = lexp(as1 + ad), x2 = lexp(as2 + ad), x3 = lexp(as3 + ad);
                acc0 += x0 * __uint_as_float(h0 << 16);
                acc1 += x0 * __uint_as_float(h0 & 0xffff0000u);
                acc0 += x1 * __uint_as_float(h1 << 16);
                acc1 += x1 * __uint_as_float(h1 & 0xffff0000u);
                acc0 += x2 * __uint_as_float(h2 << 16);
                acc1 += x2 * __uint_as_float(h2 & 0xffff0000u);
                acc0 += x3 * __uint_as_float(h3 << 16);
                acc1 += x3 * __uint_as_float(h3 & 0xffff0000u);
                dsum += x0 + x1 + x2 + x3;
            }
            for (; e < e1; ++e) {
                int s = sorted[e];
                float xe = lexp(a_s[s * 4 + hh] + ad);
                unsigned hs = *reinterpret_cast<const unsigned*>(h + (long)s * HC + 2 * lane);
                acc0 += xe * __uint_as_float(hs << 16);
                acc1 += xe * __uint_as_float(hs & 0xffff0000u);
                dsum += xe;
            }

            float inv = 1.f / dsum;
            float2 bg = *reinterpret_cast<const float2*>(bias_g + 2 * lane);
            float v0 = acc0 * inv + bg.x;
            float v1 = acc1 * inv + bg.y;
            v0 = v0 > 0.f ? v0 : expm1f(v0);
            v1 = v1 > 0.f ? v1 : expm1f(v1);
            unsigned pk = (unsigned)f2b(v0) | ((unsigned)f2b(v1) << 16);
            *reinterpret_cast<unsigned*>((unsigned short*)agg + (long)d * HC + 2 * lane) = pk;
        }
    }
}

// ---------------- fused MLP (R12-verified): out = softmax(leaky(leaky(leaky(agg@W1+b1)@W2+b2)@W3+b3)) ----------------
__global__ __launch_bounds__(256) void k_mlp(const __hip_bfloat16* __restrict__ A,
                                             const __hip_bfloat16* __restrict__ W1t,
                                             const __hip_bfloat16* __restrict__ W2t,
                                             const float* __restrict__ b1,
                                             const float* __restrict__ b2,
                                             const float* __restrict__ W3,
                                             const float* __restrict__ b3,
                                             float* __restrict__ out, int M)
{
    __shared__ unsigned short As[2][64 * PS];
    __shared__ unsigned short Bs[2][128 * PS];
    __shared__ unsigned short x1s[64 * 264];
    __shared__ float w3s[1280];

    const int t = threadIdx.x;
    const int row0 = blockIdx.x * 64;
    const int wave = t >> 6, lane = t & 63;
    const int wm = (wave >> 1) * 32, wn = (wave & 1) * 64;
    const int lm = lane & 15, kq = lane >> 4;

    for (int i = t; i < 1280; i += 256) w3s[i] = W3[i];    // [128][10] fp32

    ARegs<__hip_bfloat16> aR;
    uint4 bR[2];

    // ---------- phase 1: x1s = leaky(agg @ W1 + b1), halves cp=0,1 ----------
    #pragma unroll 1
    for (int cp = 0; cp < 2; ++cp) {
        floatx4 acc[2][4];
        #pragma unroll
        for (int i = 0; i < 2; ++i)
            #pragma unroll
            for (int j = 0; j < 4; ++j) acc[i][j] = 0.f;

        loadA_r(A, aR, t, row0, M, 128, 0);
        loadB_r(W1t, bR, t, cp * 128, 256, 128, 0);
        int b = 0;
        #pragma unroll 1
        for (int it = 0; it < 4; ++it) {
            writeA_r(As[b], aR, t);
            writeB_r(Bs[b], bR, t);
            if (it + 1 < 4) {
                loadA_r(A, aR, t, row0, M, 128, (it + 1) * 32);
                loadB_r(W1t, bR, t, cp * 128, 256, 128, (it + 1) * 32);
            }
            asm volatile("s_waitcnt lgkmcnt(0)" ::: "memory");
            __builtin_amdgcn_s_barrier();
            __builtin_amdgcn_sched_barrier(0);

            bf16x8 af[2], bf[4];
            #pragma unroll
            for (int i = 0; i < 2; ++i)
                af[i] = *reinterpret_cast<const bf16x8*>(&As[b][(wm + i * 16 + lm) * PS + kq * 8]);
            #pragma unroll
            for (int j = 0; j < 4; ++j)
                bf[j] = *reinterpret_cast<const bf16x8*>(&Bs[b][(wn + j * 16 + lm) * PS + kq * 8]);
            #pragma unroll
            for (int i = 0; i < 2; ++i)
                #pragma unroll
                for (int j = 0; j < 4; ++j)
                    acc[i][j] = __builtin_amdgcn_mfma_f32_16x16x32_bf16(af[i], bf[j], acc[i][j], 0, 0, 0);
            b ^= 1;
        }
        #pragma unroll
        for (int i = 0; i < 2; ++i)
            #pragma unroll
            for (int r = 0; r < 4; ++r) {
                int lrow = wm + i * 16 + kq * 4 + r;
                #pragma unroll
                for (int j = 0; j < 4; ++j) {
                    int gc = cp * 128 + wn + j * 16 + lm;
                    float v = acc[i][j][r] + b1[gc];
                    v = v > 0.f ? v : 0.01f * v;
                    x1s[lrow * 264 + gc] = f2b(v);
                }
            }
    }

    loadB_r(W2t, bR, t, 0, 128, 256, 0);
    __syncthreads();

    // ---------- phase 2: x2 = leaky(x1 @ W2 + b2), K=256, A from x1s ----------
    floatx4 acc[2][4];
    #pragma unroll
    for (int i = 0; i < 2; ++i)
        #pragma unroll
        for (int j = 0; j < 4; ++j) acc[i][j] = 0.f;

    int b = 0;
    #pragma unroll 1
    for (int it = 0; it < 8; ++it) {
        writeB_r(Bs[b], bR, t);
        if (it + 1 < 8) loadB_r(W2t, bR, t, 0, 128, 256, (it + 1) * 32);
        asm volatile("s_waitcnt lgkmcnt(0)" ::: "memory");
        __builtin_amdgcn_s_barrier();
        __builtin_amdgcn_sched_barrier(0);

        bf16x8 af[2], bf[4];
        #pragma unroll
        for (int i = 0; i < 2; ++i)
            af[i] = *reinterpret_cast<const bf16x8*>(&x1s[(wm + i * 16 + lm) * 264 + it * 32 + kq * 8]);
        #pragma unroll
        for (int j = 0; j < 4; ++j)
            bf[j] = *reinterpret_cast<const bf16x8*>(&Bs[b][(wn + j * 16 + lm) * PS + kq * 8]);
        #pragma unroll
        for (int i = 0; i < 2; ++i)
            #pragma unroll
            for (int j = 0; j < 4; ++j)
                acc[i][j] = __builtin_amdgcn_mfma_f32_16x16x32_bf16(af[i], bf[j], acc[i][j], 0, 0, 0);
        b ^= 1;
    }

    __syncthreads();                       // all waves' x1s reads drained before aliasing
    unsigned short* x2s = x1s;             // x2 tile, stride 130
    #pragma unroll
    for (int i = 0; i < 2; ++i)
        #pragma unroll
        for (int r = 0; r < 4; ++r) {
            int lrow = wm + i * 16 + kq * 4 + r;
            #pragma unroll
            for (int j = 0; j < 4; ++j) {
                int gc = wn + j * 16 + lm;
                float v = acc[i][j][r] + b2[gc];
                v = v > 0.f ? v : 0.01f * v;
                x2s[lrow * 130 + gc] = f2b(v);
            }
        }
    __syncthreads();

    // ---------- final: out = softmax(leaky(x2 @ W3 + b3)) ----------
    if (t < 64) {
        int grow = row0 + t;
        if (grow < M) {
            float l[10];
            #pragma unroll
            for (int j = 0; j < 10; ++j) l[j] = b3[j];
            #pragma unroll 8
            for (int c = 0; c < 128; ++c) {
                float xv = b2f(x2s[t * 130 + c]);
                const float* wr = &w3s[c * 10];
                #pragma unroll
                for (int j = 0; j < 10; ++j) l[j] += xv * wr[j];
            }
            float m = -1e30f;
            #pragma unroll
            for (int j = 0; j < 10; ++j) {
                float v = l[j];
                v = v > 0.f ? v : 0.01f * v;
                l[j] = v;
                m = fmaxf(m, v);
            }
            float sum = 0.f;
            #pragma unroll
            for (int j = 0; j < 10; ++j) { l[j] = __expf(l[j] - m); sum += l[j]; }
            float inv = 1.f / sum;
            #pragma unroll
            for (int j = 0; j < 10; ++j) out[(long)grow * 10 + j] = l[j] * inv;
        }
    }
}

extern "C" void kernel_launch(void* const* d_in, const int* in_sizes, int n_in,
                              void* d_out, int out_size, void* d_ws, size_t ws_size,
                              hipStream_t stream)
{
    const float* x       = (const float*)d_in[0];
    const int*   ei      = (const int*)d_in[1];
    const float* fb      = (const float*)d_in[2];
    const float* Wg      = (const float*)d_in[3];
    const float* bias_g  = (const float*)d_in[4];
    const float* att_src = (const float*)d_in[5];
    const float* att_dst = (const float*)d_in[6];
    const float* W1      = (const float*)d_in[7];
    const float* b1      = (const float*)d_in[8];
    const float* W2      = (const float*)d_in[9];
    const float* b2      = (const float*)d_in[10];
    const float* W3      = (const float*)d_in[11];
    const float* b3      = (const float*)d_in[12];
    float* out = (float*)d_out;
    float* ws = (float*)d_ws;

    // workspace layout (float units)
    float* a_s = ws + 0;                                        //   200,000 [N,4]
    float* a_d = ws + 200000;                                   //   200,000 [N,4]
    __hip_bfloat16* fbWgT = (__hip_bfloat16*)(ws + 400000);     //   [128][544] bf16 (34,816 f)
    __hip_bfloat16* W1T   = (__hip_bfloat16*)(ws + 434816);     //   [256][128] bf16 (16,384 f)
    __hip_bfloat16* W2T   = (__hip_bfloat16*)(ws + 451200);     //   [128][256] bf16 (16,384 f)
    int* hist   = (int*)(ws + 467584);                          //    50,000 (cursor aliases)
    int* startA = (int*)(ws + 517584);                          //    50,004
    int* sorted = (int*)(ws + 567720);                          //   800,000
    __hip_bfloat16* hbufB = (__hip_bfloat16*)(ws + 1367720);    //   [N,128] bf16 (3,200,000 f)
    __hip_bfloat16* aggB  = (__hip_bfloat16*)(ws + 4567720);    //   [N,128] bf16 (3,200,000 f)
    int* aux    = (int*)(ws + 7767720);                         //       256 (scan chunk totals)
    int* cursor = hist;                                         //   alias (hist dead after scan)
    if (ws_size < (size_t)14167720 * sizeof(float)) return;     //   diagnostic: leaves out zeroed

    // zero fbWgT (K-pad zeros) .. hist (contiguous region)
    hipMemsetAsync(ws + 400000, 0, (size_t)117584 * sizeof(float), stream);

    // prep: fbWgT + W1T + W2T in one launch
    k_prep<<<274, 256, 0, stream>>>(fb, Wg, fbWgT, W1, W1T, W2, W2T);

    // h = x @ fbWg + fused attention coeffs; blocks >= 782 do the edge histogram
    mgemm<4, float, __hip_bfloat16><<<dim3(782 + (EE + 255) / 256, 1), 256, 0, stream>>>(
        x, fbWgT, hbufB, NN, HC, NFR, 544, nullptr, att_src, att_dst, a_s, a_d, ei, hist);

    // cooperative: scan -> fill -> agg (one launch, grid.sync between phases)
    {
        void* kArgs[] = { (void*)&hist, (void*)&startA, (void*)&cursor, (void*)&aux,
                          (void*)&ei, (void*)&sorted, (void*)&a_s, (void*)&a_d,
                          (void*)&hbufB, (void*)&bias_g, (void*)&aggB };
        hipLaunchCooperativeKernel((void*)k_graph, dim3(1024), dim3(256), kArgs, 0, stream);
    }

    // fused MLP: agg -> (W1,b1,leaky) -> (W2,b2,leaky) -> (W3,b3,leaky) -> softmax -> out
    k_mlp<<<782, 256, 0, stream>>>(aggB, W1T, W2T, b1, b2, W3, b3, out, NN);
}

// Round 14
// 363.310 us; speedup vs baseline: 2.3571x; 2.3571x over previous
//
#include <hip/hip_runtime.h>
#include <hip/hip_bf16.h>

// Problem constants
#define NN 50000
#define EE 800000
#define NFR 513
#define NMEL 128
#define HC 128      // H*C = 4*32

typedef __bf16 bf16x8 __attribute__((ext_vector_type(8)));
typedef float floatx4 __attribute__((ext_vector_type(4)));

// 16-byte load at 4-byte alignment (x rows are 2052 B = 4B-aligned)
struct __attribute__((packed, aligned(4))) u4a { unsigned x, y, z, w; };

__device__ __forceinline__ unsigned short f2b(float f) {   // RNE fp32->bf16 bits
    unsigned u = __float_as_uint(f);
    u = (u + 0x7FFFu + ((u >> 16) & 1u)) >> 16;
    return (unsigned short)u;
}
__device__ __forceinline__ unsigned short f2bu(unsigned u) {  // RNE on raw fp32 bits
    u = (u + 0x7FFFu + ((u >> 16) & 1u)) >> 16;
    return (unsigned short)u;
}
__device__ __forceinline__ float b2f(unsigned short s) {
    return __uint_as_float(((unsigned)s) << 16);
}
__device__ __forceinline__ float lexp(float a) {           // exp(leaky_relu(a, 0.2))
    a = a > 0.f ? a : 0.2f * a;
    return __expf(a);
}
__device__ __forceinline__ void stf(__hip_bfloat16* p, long i, float v) {
    ((unsigned short*)p)[i] = f2b(v);
}

// ---------------- k_prep: fused {fbWgT = (fb@Wg)^T bf16 pad-544} + {W1T} + {W2T} ----------------
// (R13-verified correct.) blockIdx ranges: [0,18) gemm tiles; [18,146) W1T; [146,274) W2T.
__global__ __launch_bounds__(256) void k_prep(const float* __restrict__ fb, const float* __restrict__ Wg,
                                              __hip_bfloat16* __restrict__ fbWgT,
                                              const float* __restrict__ W1, __hip_bfloat16* __restrict__ W1T,
                                              const float* __restrict__ W2, __hip_bfloat16* __restrict__ W2T)
{
    const int b = blockIdx.x, t = threadIdx.x;
    if (b >= 18) {
        if (b < 146) {      // W1T[n*128+k] = bf16(W1[k*256+n])
            int id = (b - 18) * 256 + t;
            int n = id >> 7, k = id & 127;
            ((unsigned short*)W1T)[id] = f2b(W1[(long)k * 256 + n]);
        } else {            // W2T[n*256+k] = bf16(W2[k*128+n])
            int id = (b - 146) * 256 + t;
            int n = id >> 8, k = id & 255;
            ((unsigned short*)W2T)[id] = f2b(W2[(long)k * 128 + n]);
        }
        return;             // before any barrier — block-uniform
    }
    __shared__ float As[16][68];
    __shared__ float Bs[16][68];
    const int row0 = (b % 9) * 64;
    const int col0 = (b / 9) * 64;
    const int tc = t & 15, tr = t >> 4;
    float acc[4][4] = {};

    for (int kb = 0; kb < NMEL; kb += 16) {
        #pragma unroll
        for (int i = 0; i < 4; ++i) {
            int idx = i * 256 + t;
            int r = idx >> 4, k = idx & 15;
            int gr = row0 + r, gk = kb + k;
            float v = 0.f;
            if (gr < NFR) v = fb[(long)gr * NMEL + gk];
            As[k][r] = v;
        }
        #pragma unroll
        for (int i = 0; i < 4; ++i) {
            int idx = i * 256 + t;
            int c = idx & 63, k = idx >> 6;
            int gk = kb + k, gc = col0 + c;
            Bs[k][c] = Wg[(long)gk * HC + gc];
        }
        __syncthreads();
        #pragma unroll
        for (int kk = 0; kk < 16; ++kk) {
            float4 av = *reinterpret_cast<const float4*>(&As[kk][tr << 2]);
            float4 bv = *reinterpret_cast<const float4*>(&Bs[kk][tc << 2]);
            float a[4] = {av.x, av.y, av.z, av.w};
            float bb[4] = {bv.x, bv.y, bv.z, bv.w};
            #pragma unroll
            for (int i = 0; i < 4; ++i)
                #pragma unroll
                for (int j = 0; j < 4; ++j)
                    acc[i][j] += a[i] * bb[j];
        }
        __syncthreads();
    }
    #pragma unroll
    for (int i = 0; i < 4; ++i) {
        int gr = row0 + (tr << 2) + i;
        if (gr >= NFR) continue;
        #pragma unroll
        for (int j = 0; j < 4; ++j) {
            int gc = col0 + (tc << 2) + j;
            ((unsigned short*)fbWgT)[(long)gc * 544 + gr] = f2b(acc[i][j]);
        }
    }
}

// ---------------- MFMA bf16 GEMM: C[M,Nn] = A[M,K] @ Bt[Nn,KB]^T ----------------
// R3/R9 structure; EPI=4 = fused attention coeffs (R11-verified) + absorbed k_hist
// (R13-verified): blocks >= 782 do the edge histogram and exit before any barrier.
#define PS 40   // LDS row stride in bf16 units (80 B) -> 2-way bank conflicts only (free)

template<typename T> struct ARegs;
template<> struct ARegs<float> { unsigned v[8]; };        // raw fp32 bits
template<> struct ARegs<__hip_bfloat16> { uint4 v; };

__device__ __forceinline__ void loadA_r(const float* __restrict__ A, ARegs<float>& r, int t,
                                        int row0, int M, int K, int kb)
{
    #pragma unroll
    for (int g = 0; g < 2; ++g) {
        int q = g * 256 + t;            // 0..511 quads (64 rows x 8 quads of 16B)
        int row = q >> 3, k4 = (q & 7) * 4;
        int gr = row0 + row, gk = kb + k4;
        unsigned f0 = 0, f1 = 0, f2 = 0, f3 = 0;
        if (gr < M) {
            const float* ap = A + (long)gr * K + gk;
            if (gk + 3 < K) {           // vector path: single dwordx4 at 4B alignment
                u4a u = *reinterpret_cast<const u4a*>(ap);
                f0 = u.x; f1 = u.y; f2 = u.z; f3 = u.w;
            } else {                    // K-boundary chunk (last kb iter only)
                if (gk + 0 < K) f0 = __float_as_uint(ap[0]);
                if (gk + 1 < K) f1 = __float_as_uint(ap[1]);
                if (gk + 2 < K) f2 = __float_as_uint(ap[2]);
            }
        }
        r.v[g * 4 + 0] = f0; r.v[g * 4 + 1] = f1;
        r.v[g * 4 + 2] = f2; r.v[g * 4 + 3] = f3;
    }
}

__device__ __forceinline__ void writeA_r(unsigned short* As, const ARegs<float>& r, int t)
{
    #pragma unroll
    for (int g = 0; g < 2; ++g) {
        int q = g * 256 + t;
        int row = q >> 3, k4 = (q & 7) * 4;
        ushort4 pk;
        pk.x = f2bu(r.v[g * 4 + 0]); pk.y = f2bu(r.v[g * 4 + 1]);
        pk.z = f2bu(r.v[g * 4 + 2]); pk.w = f2bu(r.v[g * 4 + 3]);
        *reinterpret_cast<ushort4*>(&As[row * PS + k4]) = pk;
    }
}

__device__ __forceinline__ void loadA_r(const __hip_bfloat16* __restrict__ A, ARegs<__hip_bfloat16>& r,
                                        int t, int row0, int M, int K, int kb)
{
    int row = t >> 2, k8 = (t & 3) * 8;  // 256 16B-chunks (64 rows x 4)
    int gr = row0 + row;
    uint4 val = make_uint4(0, 0, 0, 0);
    if (gr < M) val = *reinterpret_cast<const uint4*>(A + (long)gr * K + kb + k8);
    r.v = val;
}

__device__ __forceinline__ void writeA_r(unsigned short* As, const ARegs<__hip_bfloat16>& r, int t)
{
    int row = t >> 2, k8 = (t & 3) * 8;
    *reinterpret_cast<uint4*>(&As[row * PS + k8]) = r.v;
}

__device__ __forceinline__ void loadB_r(const __hip_bfloat16* __restrict__ Bt, uint4* bR, int t,
                                        int col0, int Nn, int KB, int kb)
{
    #pragma unroll
    for (int g = 0; g < 2; ++g) {
        int c = g * 256 + t;            // 0..511 16B-chunks (128 rows x 4)
        int row = c >> 2, k8 = (c & 3) * 8;
        int gn = col0 + row;
        uint4 val = make_uint4(0, 0, 0, 0);
        if (gn < Nn) val = *reinterpret_cast<const uint4*>(Bt + (long)gn * KB + kb + k8);
        bR[g] = val;
    }
}

__device__ __forceinline__ void writeB_r(unsigned short* Bs, const uint4* bR, int t)
{
    #pragma unroll
    for (int g = 0; g < 2; ++g) {
        int c = g * 256 + t;
        int row = c >> 2, k8 = (c & 3) * 8;
        *reinterpret_cast<uint4*>(&Bs[row * PS + k8]) = bR[g];
    }
}

// EPI: 4 = plain C + fused attention coeffs + absorbed k_hist (blocks >= 782)
template<int EPI, typename TA, typename TC>
__global__ __launch_bounds__(256) void mgemm(const TA* __restrict__ A,
                                             const __hip_bfloat16* __restrict__ Bt,
                                             TC* __restrict__ C,
                                             int M, int Nn, int K, int KB,
                                             const float* __restrict__ bias,
                                             const float* __restrict__ pf1,
                                             const float* __restrict__ pf2,
                                             float* __restrict__ po1,
                                             float* __restrict__ po2,
                                             const int* __restrict__ ei,
                                             int* __restrict__ hist)
{
    if (EPI == 4 && blockIdx.x >= 782) {
        int e = (blockIdx.x - 782) * 256 + (int)threadIdx.x;
        if (e < EE) atomicAdd(&hist[ei[EE + e]], 1);
        return;                          // before any barrier — block-uniform
    }

    __shared__ unsigned short As[2][64 * PS];
    __shared__ unsigned short Bs[2][128 * PS];

    const int t = threadIdx.x;
    const int row0 = blockIdx.x * 64;
    const int col0 = blockIdx.y * 128;
    const int wave = t >> 6, lane = t & 63;
    const int wm = (wave >> 1) * 32, wn = (wave & 1) * 64;
    const int lm = lane & 15, kq = lane >> 4;

    floatx4 acc[2][4];
    #pragma unroll
    for (int i = 0; i < 2; ++i)
        #pragma unroll
        for (int j = 0; j < 4; ++j)
            acc[i][j] = 0.f;

    ARegs<TA> aR;
    uint4 bR[2];
    loadA_r(A, aR, t, row0, M, K, 0);
    loadB_r(Bt, bR, t, col0, Nn, KB, 0);

    const int nIter = KB >> 5;
    int b = 0;
    for (int it = 0; it < nIter; ++it) {
        writeA_r(As[b], aR, t);
        writeB_r(Bs[b], bR, t);
        if (it + 1 < nIter) {
            loadA_r(A, aR, t, row0, M, K, (it + 1) * 32);
            loadB_r(Bt, bR, t, col0, Nn, KB, (it + 1) * 32);
        }
        asm volatile("s_waitcnt lgkmcnt(0)" ::: "memory");
        __builtin_amdgcn_s_barrier();
        __builtin_amdgcn_sched_barrier(0);

        bf16x8 af[2], bf[4];
        #pragma unroll
        for (int i = 0; i < 2; ++i)
            af[i] = *reinterpret_cast<const bf16x8*>(&As[b][(wm + i * 16 + lm) * PS + kq * 8]);
        #pragma unroll
        for (int j = 0; j < 4; ++j)
            bf[j] = *reinterpret_cast<const bf16x8*>(&Bs[b][(wn + j * 16 + lm) * PS + kq * 8]);
        #pragma unroll
        for (int i = 0; i < 2; ++i)
            #pragma unroll
            for (int j = 0; j < 4; ++j)
                acc[i][j] = __builtin_amdgcn_mfma_f32_16x16x32_bf16(af[i], bf[j], acc[i][j], 0, 0, 0);
        b ^= 1;
    }

    // ---- epilogue: C write (verified mapping row=wm+i*16+kq*4+r, col=wn+j*16+lm) ----
    #pragma unroll
    for (int i = 0; i < 2; ++i) {
        #pragma unroll
        for (int r = 0; r < 4; ++r) {
            int gr = row0 + wm + i * 16 + kq * 4 + r;
            if (gr >= M) continue;
            #pragma unroll
            for (int j = 0; j < 4; ++j) {
                int gc = col0 + wn + j * 16 + lm;
                float v = acc[i][j][r];
                if (EPI == 1) { v += bias[gc]; v = v > 0.f ? v : 0.01f * v; }
                stf(C, (long)gr * Nn + gc, v);
            }
        }
    }

    // ---- EPI=4: fused attention coefficients from acc (R11-verified) ----
    if (EPI == 4) {
        float wsv[4], wdv[4];
        #pragma unroll
        for (int j = 0; j < 4; ++j) {
            int gc = wn + j * 16 + lm;      // col0 == 0 for mgemm#1
            wsv[j] = pf1[gc];
            wdv[j] = pf2[gc];
        }
        #pragma unroll
        for (int i = 0; i < 2; ++i) {
            #pragma unroll
            for (int r = 0; r < 4; ++r) {
                float s0 = acc[i][0][r] * wsv[0] + acc[i][1][r] * wsv[1];   // head wn>>5
                float s1 = acc[i][2][r] * wsv[2] + acc[i][3][r] * wsv[3];   // head (wn>>5)+1
                float d0 = acc[i][0][r] * wdv[0] + acc[i][1][r] * wdv[1];
                float d1 = acc[i][2][r] * wdv[2] + acc[i][3][r] * wdv[3];
                #pragma unroll
                for (int m = 1; m < 16; m <<= 1) {
                    s0 += __shfl_xor(s0, m); s1 += __shfl_xor(s1, m);
                    d0 += __shfl_xor(d0, m); d1 += __shfl_xor(d1, m);
                }
                if (lm == 0) {
                    int grow = row0 + wm + i * 16 + kq * 4 + r;
                    if (grow < M) {
                        int h0 = wn >> 5;                 // 0 or 2
                        po1[grow * 4 + h0]     = s0;
                        po1[grow * 4 + h0 + 1] = s1;
                        po2[grow * 4 + h0]     = d0;
                        po2[grow * 4 + h0 + 1] = d1;
                    }
                }
            }
        }
    }
}

// ---------------- CSR build (R11/R12-verified standalone kernels; cooperative fusion
// REVERTED — R13 measured it at 571us: the 1024-block co-residency cap cut the gather's
// wave parallelism 12x. k_agg needs 50,000 waves (one per node) for latency hiding.) ----------------
__global__ __launch_bounds__(512) void k_scan1(const int* __restrict__ hist, int* __restrict__ start,
                                               int* __restrict__ aux)
{
    __shared__ int sm[512];
    int t = threadIdx.x, i = blockIdx.x * 512 + t;
    int v = (i < NN) ? hist[i] : 0;
    sm[t] = v;
    __syncthreads();
    for (int off = 1; off < 512; off <<= 1) {
        int x = (t >= off) ? sm[t - off] : 0;
        __syncthreads();
        sm[t] += x;
        __syncthreads();
    }
    if (i < NN) start[i] = sm[t] - v;   // exclusive
    if (t == 511) aux[blockIdx.x] = sm[511];
}

// wave-parallel exclusive scan of 98 block sums
__global__ void k_scan2(int* __restrict__ aux, int nb)
{
    int l = threadIdx.x;                 // one wave of 64
    int v0 = (l < nb) ? aux[l] : 0;
    int v1 = (64 + l < nb) ? aux[64 + l] : 0;
    int s0 = v0, s1 = v1;
    for (int off = 1; off < 64; off <<= 1) {
        int u0 = __shfl_up(s0, off);
        int u1 = __shfl_up(s1, off);
        if (l >= off) { s0 += u0; s1 += u1; }
    }
    int tot0 = __shfl(s0, 63);
    if (l < nb) aux[l] = s0 - v0;                       // exclusive
    if (64 + l < nb) aux[64 + l] = tot0 + s1 - v1;
}

__global__ __launch_bounds__(512) void k_scan3(int* __restrict__ start, int* __restrict__ cursor,
                                               const int* __restrict__ aux)
{
    int i = blockIdx.x * 512 + threadIdx.x;
    if (i < NN) {
        int v = start[i] + aux[blockIdx.x];
        start[i] = v;
        cursor[i] = v;
    }
    if (i == 0) start[NN] = EE;
}

__global__ void k_fill(const int* __restrict__ ei, int* __restrict__ cursor, int* __restrict__ sorted)
{
    int e = blockIdx.x * 256 + threadIdx.x;
    if (e >= EE) return;
    int s = ei[e], d = ei[EE + e];
    int pos = atomicAdd(&cursor[d], 1);
    sorted[pos] = s;
}

// ---------------- per-node gather-aggregate (one wave per node — full TLP) ----------------
__global__ __launch_bounds__(256) void k_agg(const int* __restrict__ start, const int* __restrict__ sorted,
                                             const float* __restrict__ a_s, const float* __restrict__ a_d,
                                             const __hip_bfloat16* __restrict__ h,
                                             const float* __restrict__ bias_g,
                                             __hip_bfloat16* __restrict__ agg)
{
    int wave = threadIdx.x >> 6;
    int lane = threadIdx.x & 63;
    int d = blockIdx.x * 4 + wave;
    if (d >= NN) return;
    int hh = lane >> 4;                 // head of features 2*lane, 2*lane+1
    float ad = a_d[d * 4 + hh];
    int e0 = start[d], e1 = start[d + 1];

    // self-loop contribution
    float ex = lexp(a_s[d * 4 + hh] + ad);
    unsigned hv = *reinterpret_cast<const unsigned*>(h + (long)d * HC + 2 * lane);
    float acc0 = ex * __uint_as_float(hv << 16);
    float acc1 = ex * __uint_as_float(hv & 0xffff0000u);
    float dsum = ex;

    int e = e0;
    for (; e + 4 <= e1; e += 4) {
        int s0 = sorted[e + 0], s1 = sorted[e + 1], s2 = sorted[e + 2], s3 = sorted[e + 3];
        float as0 = a_s[s0 * 4 + hh], as1 = a_s[s1 * 4 + hh];
        float as2 = a_s[s2 * 4 + hh], as3 = a_s[s3 * 4 + hh];
        unsigned h0 = *reinterpret_cast<const unsigned*>(h + (long)s0 * HC + 2 * lane);
        unsigned h1 = *reinterpret_cast<const unsigned*>(h + (long)s1 * HC + 2 * lane);
        unsigned h2 = *reinterpret_cast<const unsigned*>(h + (long)s2 * HC + 2 * lane);
        unsigned h3 = *reinterpret_cast<const unsigned*>(h + (long)s3 * HC + 2 * lane);
        float x0 = lexp(as0 + ad), x1 = lexp(as1 + ad), x2 = lexp(as2 + ad), x3 = lexp(as3 + ad);
        acc0 += x0 * __uint_as_float(h0 << 16);
        acc1 += x0 * __uint_as_float(h0 & 0xffff0000u);
        acc0 += x1 * __uint_as_float(h1 << 16);
        acc1 += x1 * __uint_as_float(h1 & 0xffff0000u);
        acc0 += x2 * __uint_as_float(h2 << 16);
        acc1 += x2 * __uint_as_float(h2 & 0xffff0000u);
        acc0 += x3 * __uint_as_float(h3 << 16);
        acc1 += x3 * __uint_as_float(h3 & 0xffff0000u);
        dsum += x0 + x1 + x2 + x3;
    }
    for (; e < e1; ++e) {
        int s = sorted[e];
        float xe = lexp(a_s[s * 4 + hh] + ad);
        unsigned hs = *reinterpret_cast<const unsigned*>(h + (long)s * HC + 2 * lane);
        acc0 += xe * __uint_as_float(hs << 16);
        acc1 += xe * __uint_as_float(hs & 0xffff0000u);
        dsum += xe;
    }

    float inv = 1.f / dsum;
    float2 bg = *reinterpret_cast<const float2*>(bias_g + 2 * lane);
    float v0 = acc0 * inv + bg.x;
    float v1 = acc1 * inv + bg.y;
    v0 = v0 > 0.f ? v0 : expm1f(v0);
    v1 = v1 > 0.f ? v1 : expm1f(v1);
    unsigned pk = (unsigned)f2b(v0) | ((unsigned)f2b(v1) << 16);
    *reinterpret_cast<unsigned*>((unsigned short*)agg + (long)d * HC + 2 * lane) = pk;
}

// ---------------- fused MLP (R12-verified): out = softmax(leaky(leaky(leaky(agg@W1+b1)@W2+b2)@W3+b3)) ----------------
__global__ __launch_bounds__(256) void k_mlp(const __hip_bfloat16* __restrict__ A,
                                             const __hip_bfloat16* __restrict__ W1t,
                                             const __hip_bfloat16* __restrict__ W2t,
                                             const float* __restrict__ b1,
                                             const float* __restrict__ b2,
                                             const float* __restrict__ W3,
                                             const float* __restrict__ b3,
                                             float* __restrict__ out, int M)
{
    __shared__ unsigned short As[2][64 * PS];
    __shared__ unsigned short Bs[2][128 * PS];
    __shared__ unsigned short x1s[64 * 264];
    __shared__ float w3s[1280];

    const int t = threadIdx.x;
    const int row0 = blockIdx.x * 64;
    const int wave = t >> 6, lane = t & 63;
    const int wm = (wave >> 1) * 32, wn = (wave & 1) * 64;
    const int lm = lane & 15, kq = lane >> 4;

    for (int i = t; i < 1280; i += 256) w3s[i] = W3[i];    // [128][10] fp32

    ARegs<__hip_bfloat16> aR;
    uint4 bR[2];

    // ---------- phase 1: x1s = leaky(agg @ W1 + b1), halves cp=0,1 ----------
    #pragma unroll 1
    for (int cp = 0; cp < 2; ++cp) {
        floatx4 acc[2][4];
        #pragma unroll
        for (int i = 0; i < 2; ++i)
            #pragma unroll
            for (int j = 0; j < 4; ++j) acc[i][j] = 0.f;

        loadA_r(A, aR, t, row0, M, 128, 0);
        loadB_r(W1t, bR, t, cp * 128, 256, 128, 0);
        int b = 0;
        #pragma unroll 1
        for (int it = 0; it < 4; ++it) {
            writeA_r(As[b], aR, t);
            writeB_r(Bs[b], bR, t);
            if (it + 1 < 4) {
                loadA_r(A, aR, t, row0, M, 128, (it + 1) * 32);
                loadB_r(W1t, bR, t, cp * 128, 256, 128, (it + 1) * 32);
            }
            asm volatile("s_waitcnt lgkmcnt(0)" ::: "memory");
            __builtin_amdgcn_s_barrier();
            __builtin_amdgcn_sched_barrier(0);

            bf16x8 af[2], bf[4];
            #pragma unroll
            for (int i = 0; i < 2; ++i)
                af[i] = *reinterpret_cast<const bf16x8*>(&As[b][(wm + i * 16 + lm) * PS + kq * 8]);
            #pragma unroll
            for (int j = 0; j < 4; ++j)
                bf[j] = *reinterpret_cast<const bf16x8*>(&Bs[b][(wn + j * 16 + lm) * PS + kq * 8]);
            #pragma unroll
            for (int i = 0; i < 2; ++i)
                #pragma unroll
                for (int j = 0; j < 4; ++j)
                    acc[i][j] = __builtin_amdgcn_mfma_f32_16x16x32_bf16(af[i], bf[j], acc[i][j], 0, 0, 0);
            b ^= 1;
        }
        #pragma unroll
        for (int i = 0; i < 2; ++i)
            #pragma unroll
            for (int r = 0; r < 4; ++r) {
                int lrow = wm + i * 16 + kq * 4 + r;
                #pragma unroll
                for (int j = 0; j < 4; ++j) {
                    int gc = cp * 128 + wn + j * 16 + lm;
                    float v = acc[i][j][r] + b1[gc];
                    v = v > 0.f ? v : 0.01f * v;
                    x1s[lrow * 264 + gc] = f2b(v);
                }
            }
    }

    loadB_r(W2t, bR, t, 0, 128, 256, 0);
    __syncthreads();

    // ---------- phase 2: x2 = leaky(x1 @ W2 + b2), K=256, A from x1s ----------
    floatx4 acc[2][4];
    #pragma unroll
    for (int i = 0; i < 2; ++i)
        #pragma unroll
        for (int j = 0; j < 4; ++j) acc[i][j] = 0.f;

    int b = 0;
    #pragma unroll 1
    for (int it = 0; it < 8; ++it) {
        writeB_r(Bs[b], bR, t);
        if (it + 1 < 8) loadB_r(W2t, bR, t, 0, 128, 256, (it + 1) * 32);
        asm volatile("s_waitcnt lgkmcnt(0)" ::: "memory");
        __builtin_amdgcn_s_barrier();
        __builtin_amdgcn_sched_barrier(0);

        bf16x8 af[2], bf[4];
        #pragma unroll
        for (int i = 0; i < 2; ++i)
            af[i] = *reinterpret_cast<const bf16x8*>(&x1s[(wm + i * 16 + lm) * 264 + it * 32 + kq * 8]);
        #pragma unroll
        for (int j = 0; j < 4; ++j)
            bf[j] = *reinterpret_cast<const bf16x8*>(&Bs[b][(wn + j * 16 + lm) * PS + kq * 8]);
        #pragma unroll
        for (int i = 0; i < 2; ++i)
            #pragma unroll
            for (int j = 0; j < 4; ++j)
                acc[i][j] = __builtin_amdgcn_mfma_f32_16x16x32_bf16(af[i], bf[j], acc[i][j], 0, 0, 0);
        b ^= 1;
    }

    __syncthreads();                       // all waves' x1s reads drained before aliasing
    unsigned short* x2s = x1s;             // x2 tile, stride 130
    #pragma unroll
    for (int i = 0; i < 2; ++i)
        #pragma unroll
        for (int r = 0; r < 4; ++r) {
            int lrow = wm + i * 16 + kq * 4 + r;
            #pragma unroll
            for (int j = 0; j < 4; ++j) {
                int gc = wn + j * 16 + lm;
                float v = acc[i][j][r] + b2[gc];
                v = v > 0.f ? v : 0.01f * v;
                x2s[lrow * 130 + gc] = f2b(v);
            }
        }
    __syncthreads();

    // ---------- final: out = softmax(leaky(x2 @ W3 + b3)) ----------
    if (t < 64) {
        int grow = row0 + t;
        if (grow < M) {
            float l[10];
            #pragma unroll
            for (int j = 0; j < 10; ++j) l[j] = b3[j];
            #pragma unroll 8
            for (int c = 0; c < 128; ++c) {
                float xv = b2f(x2s[t * 130 + c]);
                const float* wr = &w3s[c * 10];
                #pragma unroll
                for (int j = 0; j < 10; ++j) l[j] += xv * wr[j];
            }
            float m = -1e30f;
            #pragma unroll
            for (int j = 0; j < 10; ++j) {
                float v = l[j];
                v = v > 0.f ? v : 0.01f * v;
                l[j] = v;
                m = fmaxf(m, v);
            }
            float sum = 0.f;
            #pragma unroll
            for (int j = 0; j < 10; ++j) { l[j] = __expf(l[j] - m); sum += l[j]; }
            float inv = 1.f / sum;
            #pragma unroll
            for (int j = 0; j < 10; ++j) out[(long)grow * 10 + j] = l[j] * inv;
        }
    }
}

extern "C" void kernel_launch(void* const* d_in, const int* in_sizes, int n_in,
                              void* d_out, int out_size, void* d_ws, size_t ws_size,
                              hipStream_t stream)
{
    const float* x       = (const float*)d_in[0];
    const int*   ei      = (const int*)d_in[1];
    const float* fb      = (const float*)d_in[2];
    const float* Wg      = (const float*)d_in[3];
    const float* bias_g  = (const float*)d_in[4];
    const float* att_src = (const float*)d_in[5];
    const float* att_dst = (const float*)d_in[6];
    const float* W1      = (const float*)d_in[7];
    const float* b1      = (const float*)d_in[8];
    const float* W2      = (const float*)d_in[9];
    const float* b2      = (const float*)d_in[10];
    const float* W3      = (const float*)d_in[11];
    const float* b3      = (const float*)d_in[12];
    float* out = (float*)d_out;
    float* ws = (float*)d_ws;

    // workspace layout (float units)
    float* a_s = ws + 0;                                        //   200,000 [N,4]
    float* a_d = ws + 200000;                                   //   200,000 [N,4]
    __hip_bfloat16* fbWgT = (__hip_bfloat16*)(ws + 400000);     //   [128][544] bf16 (34,816 f)
    __hip_bfloat16* W1T   = (__hip_bfloat16*)(ws + 434816);     //   [256][128] bf16 (16,384 f)
    __hip_bfloat16* W2T   = (__hip_bfloat16*)(ws + 451200);     //   [128][256] bf16 (16,384 f)
    int* hist   = (int*)(ws + 467584);                          //    50,000 (cursor aliases)
    int* startA = (int*)(ws + 517584);                          //    50,004
    int* aux    = (int*)(ws + 567588);                          //       132
    int* sorted = (int*)(ws + 567720);                          //   800,000
    __hip_bfloat16* hbufB = (__hip_bfloat16*)(ws + 1367720);    //   [N,128] bf16 (3,200,000 f)
    __hip_bfloat16* aggB  = (__hip_bfloat16*)(ws + 4567720);    //   [N,128] bf16 (3,200,000 f)
    int* cursor = hist;                                         //   alias (hist dead after scan1)
    if (ws_size < (size_t)14167720 * sizeof(float)) return;     //   diagnostic: leaves out zeroed

    // zero fbWgT (K-pad zeros) .. hist (contiguous region)
    hipMemsetAsync(ws + 400000, 0, (size_t)117584 * sizeof(float), stream);

    // prep: fbWgT + W1T + W2T in one launch (R13-verified)
    k_prep<<<274, 256, 0, stream>>>(fb, Wg, fbWgT, W1, W1T, W2, W2T);

    // h = x @ fbWg + fused attention coeffs; blocks >= 782 do the edge histogram
    mgemm<4, float, __hip_bfloat16><<<dim3(782 + (EE + 255) / 256, 1), 256, 0, stream>>>(
        x, fbWgT, hbufB, NN, HC, NFR, 544, nullptr, att_src, att_dst, a_s, a_d, ei, hist);

    // CSR build (standalone kernels — full parallelism for the latency-bound phases)
    k_scan1<<<98, 512, 0, stream>>>(hist, startA, aux);
    k_scan2<<<1, 64, 0, stream>>>(aux, 98);
    k_scan3<<<98, 512, 0, stream>>>(startA, cursor, aux);
    k_fill<<<(EE + 255) / 256, 256, 0, stream>>>(ei, cursor, sorted);

    // gather-aggregate: one wave per node (50,000 waves — latency hiding via TLP)
    k_agg<<<(NN + 3) / 4, 256, 0, stream>>>(startA, sorted, a_s, a_d, hbufB, bias_g, aggB);

    // fused MLP: agg -> (W1,b1,leaky) -> (W2,b2,leaky) -> (W3,b3,leaky) -> softmax -> out
    k_mlp<<<782, 256, 0, stream>>>(aggB, W1T, W2T, b1, b2, W3, b3, out, NN);
}